// Round 4
// baseline (1110.967 us; speedup 1.0000x reference)
//
#include <hip/hip_runtime.h>

// Problem: g=4, s=4096, num_experts=16, capacity=512.
// Output tuple read back flat as f32:
//   [0]                  scalar 0.0
//   [1 .. 1+N)           float tensor [4,4096,16,512], one-hot
//   [1+N .. 1+2N)        bool tensor, same pattern (1.0f/0.0f)
// N = 4*4096*16*512 = 134217728. Total = 268435457 elements (1.074 GB).
//
// One-hot test for tensor-local index a:
//   slot = a & 511, e = (a>>9)&15, tok = (a>>13)&4095
//   is_one = (e == tok%16) && (slot == tok/16)
//
// Harness re-poisons d_out (0xAA) before every timed call -> every element
// must be written. Pure write-bound: 1.074 GB @ ~6.3 TB/s ~= 170 us floor.
// 16 float4 stores/thread (16384 blocks), 32-bit index math, unrolled,
// nontemporal streaming stores via native clang vector type (HIP float4
// is a class — the builtin rejects it).

#define TENSOR_ELEMS 134217728u
#define TOTAL_ELEMS  268435457LL
#define N_FLOAT4     67108864     // (TOTAL_ELEMS-1)/4; 1-element tail

typedef float vfloat4 __attribute__((ext_vector_type(4)));

__global__ void __launch_bounds__(256) rrg_write(vfloat4* __restrict__ out4) {
    // block covers 4096 contiguous float4s (64 KB); lane-coalesced per iter
    const unsigned base = blockIdx.x * 4096u + threadIdx.x;
#pragma unroll
    for (int k = 0; k < 16; ++k) {
        const unsigned i = base + (unsigned)k * 256u;   // float4 index
        vfloat4 v = (vfloat4)0.0f;
        const unsigned n0 = i * 4u;                     // flat element index
#pragma unroll
        for (int j = 0; j < 4; ++j) {
            const unsigned n = n0 + (unsigned)j;
            if (n >= 1u) {                    // n==0 is the 0.0 scalar
                unsigned a = n - 1u;          // tensor-local index
                if (a >= TENSOR_ELEMS) a -= TENSOR_ELEMS;  // fold bool region
                const unsigned slot = a & 511u;
                const unsigned e    = (a >> 9) & 15u;
                const unsigned tok  = (a >> 13) & 4095u;
                if (e == (tok & 15u) && slot == (tok >> 4))
                    v[j] = 1.0f;
            }
        }
        __builtin_nontemporal_store(v, out4 + i);
    }
    // tail element 268435456 (bool tensor a=134217727: slot=511, tok=4095,
    // needed slot=255 -> zero)
    if (base == 0)
        __builtin_nontemporal_store(0.0f, (float*)out4 + (TOTAL_ELEMS - 1));
}

extern "C" void kernel_launch(void* const* d_in, const int* in_sizes, int n_in,
                              void* d_out, int out_size, void* d_ws, size_t ws_size,
                              hipStream_t stream) {
    (void)d_in; (void)in_sizes; (void)n_in; (void)d_ws; (void)ws_size;
    // 67108864 float4s / (256 threads * 16 per thread) = 16384 blocks
    rrg_write<<<N_FLOAT4 / (256 * 16), 256, 0, stream>>>((vfloat4*)d_out);
}

// Round 5
// 1055.782 us; speedup vs baseline: 1.0523x; 1.0523x over previous
//
#include <hip/hip_runtime.h>

// Problem: g=4, s=4096, num_experts=16, capacity=512.
// Output tuple read back flat as f32:
//   [0]                  scalar 0.0
//   [1 .. 1+N)           float tensor [4,4096,16,512], one-hot
//   [1+N .. 1+2N)        bool tensor, same pattern (1.0f/0.0f)
// N = 4*4096*16*512 = 134217728. Total = 268435457 elements (1.074 GB).
//
// One-hot test for tensor-local index a:
//   slot = a & 511, e = (a>>9)&15, tok = (a>>13)&4095
//   is_one = (e == tok%16) && (slot == tok/16)
//
// Harness re-poisons d_out (0xAA) before every timed call -> every element
// must be written. Pure write-bound: 1.074 GB @ ~6.3 TB/s ~= 170 us floor.
//
// ROUND-2 STRUCTURE (best measured: dur 1056 us, back-solved kernel ~179 us
// ~= 6.0 TB/s): one float4 store per thread, 262144 blocks, plain stores.
// Round 4 A/B showed NT stores + 16 stores/thread REGRESS to ~234 us — keep
// plain global_store_dwordx4 and the 1-store/thread shape.

#define TENSOR_ELEMS 134217728LL
#define TOTAL_ELEMS  268435457LL
#define N_FLOAT4     67108864     // (TOTAL_ELEMS-1)/4; 1-element tail

__global__ void __launch_bounds__(256) rrg_write(float4* __restrict__ out4) {
    const int i = blockIdx.x * 256 + threadIdx.x;   // [0, 67108864)
    float4 v = make_float4(0.f, 0.f, 0.f, 0.f);
    const long long n0 = 4LL * i;   // flat output element index of lane's base
#pragma unroll
    for (int j = 0; j < 4; ++j) {
        const long long n = n0 + j;
        if (n >= 1) {                       // n==0 is the scalar (0.0)
            long long a = n - 1;            // tensor-local index
            if (a >= TENSOR_ELEMS) a -= TENSOR_ELEMS;   // fold bool region
            const int slot = (int)(a & 511);
            const int e    = (int)((a >> 9) & 15);
            const int tok  = (int)((a >> 13) & 4095);
            if (e == (tok & 15) && slot == (tok >> 4))
                (&v.x)[j] = 1.0f;
        }
    }
    out4[i] = v;
    // tail element 268435456: bool-tensor a=134217727 -> slot=511, tok=4095,
    // needed slot=255 -> not a one; write 0.
    if (i == 0)
        ((float*)out4)[TOTAL_ELEMS - 1] = 0.0f;
}

extern "C" void kernel_launch(void* const* d_in, const int* in_sizes, int n_in,
                              void* d_out, int out_size, void* d_ws, size_t ws_size,
                              hipStream_t stream) {
    (void)d_in; (void)in_sizes; (void)n_in; (void)d_ws; (void)ws_size;
    // 67108864 float4 stores / 256 threads = 262144 blocks, 1 store/thread.
    rrg_write<<<N_FLOAT4 / 256, 256, 0, stream>>>((float4*)d_out);
}